// Round 9
// baseline (322.099 us; speedup 1.0000x reference)
//
#include <hip/hip_runtime.h>
#include <hip/hip_bf16.h>
#include <hip/hip_fp16.h>

#define CHUNK 8192          // edges per radix chunk
#define WN    128           // nodes per window/bucket
#define NBMAX 512           // max buckets (N <= 65536)

typedef _Float16 f16x8 __attribute__((ext_vector_type(8)));
typedef float    f32x4 __attribute__((ext_vector_type(4)));

// ============ radix partition by dst window (2-pass, LDS-local) ============

__global__ __launch_bounds__(1024) void k_rhist(const int* __restrict__ dst, int* __restrict__ H,
                                                int E, int NC, int NB) {
    __shared__ int h[NBMAX];
    int c = blockIdx.x, t = threadIdx.x;
    for (int i = t; i < NB; i += 1024) h[i] = 0;
    __syncthreads();
    int base = c * CHUNK;
    int lim = min(CHUNK, E - base);
    for (int k = t; k < lim; k += 1024) atomicAdd(&h[dst[base + k] >> 7], 1);
    __syncthreads();
    for (int i = t; i < NB; i += 1024) H[i * NC + c] = h[i];   // bucket-major
}

__global__ __launch_bounds__(256) void k_scanA(const int* __restrict__ in, int* __restrict__ out,
                                               int* __restrict__ bsum, int n) {
    __shared__ int s[256];
    int i = blockIdx.x * 256 + threadIdx.x;
    int v = (i < n) ? in[i] : 0;
    s[threadIdx.x] = v;
    __syncthreads();
    for (int off = 1; off < 256; off <<= 1) {
        int x = (threadIdx.x >= off) ? s[threadIdx.x - off] : 0;
        __syncthreads();
        s[threadIdx.x] += x;
        __syncthreads();
    }
    if (i < n) out[i] = s[threadIdx.x] - v;
    if (threadIdx.x == 255) bsum[blockIdx.x] = s[255];
}

__global__ __launch_bounds__(512) void k_scanB(int* __restrict__ bsum, int nb) {
    __shared__ int s[512];
    int t = threadIdx.x;
    int v = (t < nb) ? bsum[t] : 0;
    s[t] = v;
    __syncthreads();
    for (int off = 1; off < 512; off <<= 1) {
        int x = (t >= off) ? s[t - off] : 0;
        __syncthreads();
        s[t] += x;
        __syncthreads();
    }
    if (t < nb) bsum[t] = s[t] - v;
}

// scanC folded into consumers: global offset = O[idx] + bsum[idx >> 8]

__global__ __launch_bounds__(1024) void k_rscatter(const int* __restrict__ src, const int* __restrict__ dst,
                                                   const int* __restrict__ O, const int* __restrict__ bsum,
                                                   int* __restrict__ packed, int E, int NC, int NB) {
    __shared__ int cur[NBMAX];
    int c = blockIdx.x, t = threadIdx.x;
    for (int i = t; i < NB; i += 1024) {
        int idx = i * NC + c;
        cur[i] = O[idx] + bsum[idx >> 8];
    }
    __syncthreads();
    int base = c * CHUNK;
    int lim = min(CHUNK, E - base);
    for (int k = t; k < lim; k += 1024) {
        int d = dst[base + k];
        int p = atomicAdd(&cur[d >> 7], 1);
        packed[p] = (src[base + k] << 7) | (d & (WN - 1));
    }
}

// per-window: packed -> per-node CSR + row_start + dinv, plus fused
// prescale epilogue: y = fp16(dinv * x) for the window's nodes.
__global__ __launch_bounds__(512) void k_wincsr(const int* __restrict__ packed,
                                                const int* __restrict__ O,
                                                const int* __restrict__ bsum,
                                                int* __restrict__ row_start,
                                                int* __restrict__ csr,
                                                float* __restrict__ dinv,
                                                const float* __restrict__ x,
                                                __half* __restrict__ y,
                                                int n, int NC, int NB, int E) {
    __shared__ int cnt[WN];
    __shared__ int ss[WN];
    __shared__ int cur[WN];
    __shared__ float sdv[WN];
    int b = blockIdx.x, t = threadIdx.x;
    int i0 = b * NC;
    int s = O[i0] + bsum[i0 >> 8];
    int e;
    if (b + 1 < NB) {
        int i1 = (b + 1) * NC;
        e = O[i1] + bsum[i1 >> 8];
    } else {
        e = E;
    }
    if (t < WN) cnt[t] = 0;
    __syncthreads();
    for (int k = s + t; k < e; k += 512) atomicAdd(&cnt[packed[k] & (WN - 1)], 1);
    __syncthreads();
    int v = (t < WN) ? cnt[t] : 0;
    if (t < WN) ss[t] = v;
    __syncthreads();
    for (int off = 1; off < WN; off <<= 1) {
        int x2 = (t >= off && t < WN) ? ss[t - off] : 0;
        __syncthreads();
        if (t < WN) ss[t] += x2;
        __syncthreads();
    }
    int node = b * WN + t;
    if (t < WN) {
        int start = s + ss[t] - v;
        cur[t] = start;
        float dv = rsqrtf((float)(cnt[t] + 1));   // +1 self-loop
        sdv[t] = dv;
        if (node < n) {
            row_start[node] = start;
            dinv[node] = dv;
        }
    }
    if (b == NB - 1 && t == 0) row_start[n] = E;
    __syncthreads();
    for (int k = s + t; k < e; k += 512) {
        int r = packed[k];
        int p = atomicAdd(&cur[r & (WN - 1)], 1);
        csr[p] = r >> 7;
    }
    // fused prescale: y[node] = fp16(dinv * x[node,:])  (64 ch = 16 float4)
    int node0 = b * WN;
    for (int i = t; i < WN * 16; i += 512) {
        int nd = i >> 4, c4 = i & 15;
        int g = node0 + nd;
        if (g < n) {
            float dv = sdv[nd];
            float4 vv = ((const float4*)x)[(size_t)g * 16 + c4];
            __half2 h0 = __floats2half2_rn(vv.x * dv, vv.y * dv);
            __half2 h1 = __floats2half2_rn(vv.z * dv, vv.w * dv);
            uint2 u;
            u.x = *(unsigned int*)&h0;
            u.y = *(unsigned int*)&h1;
            ((uint2*)y)[(size_t)g * 16 + c4] = u;
        }
    }
}

// ============ all 3 weights fp32 -> fp16 transposed in one kernel ============

__global__ __launch_bounds__(256) void k_w2h3(const float* __restrict__ W1, _Float16* __restrict__ W1t,
                                              const float* __restrict__ W2, _Float16* __restrict__ W2t,
                                              const float* __restrict__ W3, _Float16* __restrict__ W3t) {
    int idx = blockIdx.x * 256 + threadIdx.x;
    if (idx < 8192) {                       // W1: 64 x 128
        int k = idx >> 7, f = idx & 127;
        W1t[f * 64 + k] = (_Float16)W1[idx];
    } else if (idx < 24576) {               // W2: 128 x 128
        int i = idx - 8192;
        int k = i >> 7, f = i & 127;
        W2t[f * 128 + k] = (_Float16)W2[i];
    } else if (idx < 32768) {               // W3: 128 x 64
        int i = idx - 24576;
        int k = i >> 6, f = i & 63;
        W3t[f * 128 + k] = (_Float16)W3[i];
    }
}

// ============ MFMA f16 GEMM: 64 rows/block, 4 waves x 16 rows ============
// EPI 0: out = fp16(acc * dinv[row]);  EPI 1: out = fp16(relu(acc + bias[col]))
// SP: split output columns into two compact F/2-wide buffers Hl / Hh.

template <int K, int F, int EPI, bool SP>
__global__ __launch_bounds__(256) void k_gemm_mfma(const __half* __restrict__ X,
                                                   const _Float16* __restrict__ Wt,
                                                   const float* __restrict__ dinv,
                                                   const float* __restrict__ bias,
                                                   __half* __restrict__ Hl,
                                                   __half* __restrict__ Hh, int n) {
    constexpr int ROWS = 64;
    constexpr int XS   = K + 8;
    __shared__ _Float16 sX[ROWS * XS];
    __shared__ _Float16 sW[F * XS];
    int row0 = blockIdx.x * ROWS;
    int t = threadIdx.x;

    const uint4* Xg = (const uint4*)X;
    for (int i = t; i < ROWS * (K / 8); i += 256) {
        int r = i / (K / 8), k8 = i % (K / 8);
        int gr = row0 + r;
        uint4 v = (gr < n) ? Xg[(size_t)gr * (K / 8) + k8] : make_uint4(0, 0, 0, 0);
        *(uint4*)&sX[r * XS + k8 * 8] = v;
    }
    const uint4* Wg = (const uint4*)Wt;
    for (int i = t; i < F * (K / 8); i += 256) {
        int f = i / (K / 8), k8 = i % (K / 8);
        *(uint4*)&sW[f * XS + k8 * 8] = Wg[i];
    }
    __syncthreads();

    int w = t >> 6, l = t & 63;
    int wrow = w * 16;
    int lr = l & 15;
    int lk = (l >> 4) * 8;
    f32x4 acc[F / 16];
#pragma unroll
    for (int c = 0; c < F / 16; ++c) acc[c] = (f32x4){0.f, 0.f, 0.f, 0.f};

#pragma unroll
    for (int kb = 0; kb < K / 32; ++kb) {
        f16x8 a = *(const f16x8*)&sX[(wrow + lr) * XS + kb * 32 + lk];
#pragma unroll
        for (int c = 0; c < F / 16; ++c) {
            f16x8 b = *(const f16x8*)&sW[(c * 16 + lr) * XS + kb * 32 + lk];
            acc[c] = __builtin_amdgcn_mfma_f32_16x16x32_f16(a, b, acc[c], 0, 0, 0);
        }
    }

    int rbase = row0 + wrow + (l >> 4) * 4;
    if (EPI == 0) {
        float dv[4];
#pragma unroll
        for (int r = 0; r < 4; ++r) dv[r] = (rbase + r < n) ? dinv[rbase + r] : 0.f;
#pragma unroll
        for (int c = 0; c < F / 16; ++c) {
            int col = c * 16 + lr;
#pragma unroll
            for (int r = 0; r < 4; ++r) {
                int gr = rbase + r;
                if (gr < n) {
                    __half hv = __float2half(acc[c][r] * dv[r]);
                    if (SP) {
                        if (c < F / 32) Hl[(size_t)gr * (F / 2) + col] = hv;
                        else            Hh[(size_t)gr * (F / 2) + col - F / 2] = hv;
                    } else {
                        Hl[(size_t)gr * F + col] = hv;
                    }
                }
            }
        }
    } else {
#pragma unroll
        for (int c = 0; c < F / 16; ++c) {
            int col = c * 16 + lr;
            float bc = bias[col];
#pragma unroll
            for (int r = 0; r < 4; ++r) {
                int gr = rbase + r;
                if (gr < n) {
                    __half hv = __float2half(fmaxf(acc[c][r] + bc, 0.f));
                    if (SP) {
                        if (c < F / 32) Hl[(size_t)gr * (F / 2) + col] = hv;
                        else            Hh[(size_t)gr * (F / 2) + col - F / 2] = hv;
                    } else {
                        Hl[(size_t)gr * F + col] = hv;
                    }
                }
            }
        }
    }
}

// ============ CSR aggregate (fp16 gather), 64-ch compact input ============
// blockIdx.y selects {HN0,bias0,col 0} vs {HN1,bias1,col F/2} (merged halves).
// EPI 0: out = fp16(dinv*acc);  EPI 1: out = fp16(relu(dinv*acc + bias))
// POOL 1: skip OUT; atomicAdd into gsum[batch[node]] + gcnt (fused mean-pool).

__device__ __forceinline__ void acc8(float* a, uint4 v) {
    const __half2* h = (const __half2*)&v;
#pragma unroll
    for (int i = 0; i < 4; ++i) {
        float2 f = __half22float2(h[i]);
        a[2 * i]     += f.x;
        a[2 * i + 1] += f.y;
    }
}

template <int F, int EPI, int POOL>
__global__ void k_agg_h(const __half* __restrict__ HN0, const __half* __restrict__ HN1,
                        const int* __restrict__ csr, const int* __restrict__ rs,
                        const float* __restrict__ dinv,
                        const float* __restrict__ bias0, const float* __restrict__ bias1,
                        __half* __restrict__ OUT, int n, int ostride4,
                        const int* __restrict__ batch, float* __restrict__ gsum,
                        int* __restrict__ gcnt) {
    constexpr int LPN = F / 8;             // lanes per node (8 for F=64)
    constexpr int NPB = 256 / LPN;
    int half = blockIdx.y;
    const __half* HN = half ? HN1 : HN0;
    const float* bias = half ? bias1 : bias0;
    int ooff4 = half ? LPN : 0;
    int node = blockIdx.x * NPB + threadIdx.x / LPN;
    int l    = threadIdx.x % LPN;
    if (node >= n) return;
    const uint4* hn = (const uint4*)HN;
    size_t base = (size_t)node * LPN + l;
    float a[8];
    {
        uint4 v = hn[base];                // self (pre-scaled by dinv[self])
        const __half2* h = (const __half2*)&v;
#pragma unroll
        for (int i = 0; i < 4; ++i) {
            float2 f = __half22float2(h[i]);
            a[2 * i] = f.x; a[2 * i + 1] = f.y;
        }
    }
    int s = rs[node], e = rs[node + 1];
    int k = s;
    for (; k + 8 <= e; k += 8) {           // 8 gathers in flight
        int si[8];
#pragma unroll
        for (int u = 0; u < 8; ++u) si[u] = csr[k + u];
        uint4 v[8];
#pragma unroll
        for (int u = 0; u < 8; ++u) v[u] = hn[(size_t)si[u] * LPN + l];
#pragma unroll
        for (int u = 0; u < 8; ++u) acc8(a, v[u]);
    }
    for (; k + 4 <= e; k += 4) {
        int s0 = csr[k], s1 = csr[k + 1], s2 = csr[k + 2], s3 = csr[k + 3];
        uint4 v0 = hn[(size_t)s0 * LPN + l];
        uint4 v1 = hn[(size_t)s1 * LPN + l];
        uint4 v2 = hn[(size_t)s2 * LPN + l];
        uint4 v3 = hn[(size_t)s3 * LPN + l];
        acc8(a, v0); acc8(a, v1); acc8(a, v2); acc8(a, v3);
    }
    for (; k < e; ++k) acc8(a, hn[(size_t)csr[k] * LPN + l]);

    float dv = dinv[node];
    float o[8];
    if (EPI == 0) {
#pragma unroll
        for (int j = 0; j < 8; ++j) o[j] = a[j] * dv;
    } else {
        const float4* b4 = (const float4*)bias;
        float4 bb0 = b4[l * 2], bb1 = b4[l * 2 + 1];
        o[0] = fmaxf(fmaf(a[0], dv, bb0.x), 0.f);
        o[1] = fmaxf(fmaf(a[1], dv, bb0.y), 0.f);
        o[2] = fmaxf(fmaf(a[2], dv, bb0.z), 0.f);
        o[3] = fmaxf(fmaf(a[3], dv, bb0.w), 0.f);
        o[4] = fmaxf(fmaf(a[4], dv, bb1.x), 0.f);
        o[5] = fmaxf(fmaf(a[5], dv, bb1.y), 0.f);
        o[6] = fmaxf(fmaf(a[6], dv, bb1.z), 0.f);
        o[7] = fmaxf(fmaf(a[7], dv, bb1.w), 0.f);
    }
    if (POOL) {
        int bg = batch[node];
        float* gs = &gsum[bg * 64 + l * 8];
#pragma unroll
        for (int j = 0; j < 8; ++j) atomicAdd(&gs[j], o[j]);
        if (l == 0) atomicAdd(&gcnt[bg], 1);
    } else {
        uint4 u;
        __half2 p0 = __floats2half2_rn(o[0], o[1]);
        __half2 p1 = __floats2half2_rn(o[2], o[3]);
        __half2 p2 = __floats2half2_rn(o[4], o[5]);
        __half2 p3 = __floats2half2_rn(o[6], o[7]);
        u.x = *(unsigned int*)&p0; u.y = *(unsigned int*)&p1;
        u.z = *(unsigned int*)&p2; u.w = *(unsigned int*)&p3;
        ((uint4*)OUT)[(size_t)node * ostride4 + ooff4 + l] = u;
    }
}

// ============ MLP head on pooled means ============

__global__ void k_poolhead(const float* __restrict__ gsum, const int* __restrict__ gcnt,
                           const float* __restrict__ Wl1, const float* __restrict__ bl1,
                           const float* __restrict__ Wl2, const float* __restrict__ bl2,
                           float* __restrict__ out, int B) {
    __shared__ float sh[4][64];
    __shared__ float shid[4][32];
    int w = threadIdx.x >> 6;
    int lane = threadIdx.x & 63;
    int g = blockIdx.x * 4 + w;
    if (g < B) {
        float cnt = fmaxf((float)gcnt[g], 1.f);
        sh[w][lane] = gsum[g * 64 + lane] / cnt;
    }
    __syncthreads();
    if (g < B && lane < 32) {
        float a = bl1[lane];
        for (int k = 0; k < 64; ++k) a = fmaf(sh[w][k], Wl1[k * 32 + lane], a);
        shid[w][lane] = fmaxf(a, 0.f);
    }
    __syncthreads();
    if (g < B && lane < 10) {
        float a = bl2[lane];
        for (int k = 0; k < 32; ++k) a = fmaf(shid[w][k], Wl2[k * 10 + lane], a);
        out[g * 10 + lane] = a;
    }
}

// ============ launch ============

extern "C" void kernel_launch(void* const* d_in, const int* in_sizes, int n_in,
                              void* d_out, int out_size, void* d_ws, size_t ws_size,
                              hipStream_t stream) {
    const float* x    = (const float*)d_in[0];
    const int*   ei   = (const int*)d_in[1];
    const int*   batch= (const int*)d_in[2];
    const float* W1   = (const float*)d_in[3];
    const float* b1   = (const float*)d_in[4];
    const float* W2   = (const float*)d_in[5];
    const float* b2   = (const float*)d_in[6];
    const float* W3   = (const float*)d_in[7];
    const float* b3   = (const float*)d_in[8];
    const float* Wl1  = (const float*)d_in[9];
    const float* bl1  = (const float*)d_in[10];
    const float* Wl2  = (const float*)d_in[11];
    const float* bl2  = (const float*)d_in[12];

    const int N  = in_sizes[0] / 64;
    const int E  = in_sizes[1] / 2;
    const int B  = out_size / 10;
    const int NB = (N + WN - 1) / WN;
    const int NC = (E + CHUNK - 1) / CHUNK;
    const int NBNC = NB * NC;
    const int GS = (NBNC + 255) / 256;
    const int* srcI = ei;
    const int* dstI = ei + E;

    char* p = (char*)d_ws;
    auto alloc = [&](size_t bytes) {
        char* r = p;
        p += (bytes + 255) & ~(size_t)255;
        return r;
    };
    float* gsum     = (float*)alloc((size_t)B * 64 * 4);
    int*   gcnt     = (int*)alloc((size_t)B * 4);
    size_t zbytes   = (size_t)(p - (char*)d_ws);       // zero gsum+gcnt each call
    int*   H        = (int*)alloc((size_t)NBNC * 4);
    int*   O        = (int*)alloc((size_t)NBNC * 4);
    int*   bsum     = (int*)alloc(2048 * 4);
    int*   packed   = (int*)alloc((size_t)E * 4);
    int*   csr      = (int*)alloc((size_t)E * 4);
    int*   row_start= (int*)alloc((size_t)(N + 1) * 4);
    float* dinv     = (float*)alloc((size_t)N * 4);
    _Float16* W1t   = (_Float16*)alloc((size_t)64 * 128 * 2);
    _Float16* W2t   = (_Float16*)alloc((size_t)128 * 128 * 2);
    _Float16* W3t   = (_Float16*)alloc((size_t)128 * 64 * 2);
    __half* bufA    = (__half*)alloc((size_t)N * 128 * 2);
    __half* bufB    = (__half*)alloc((size_t)N * 128 * 2);
    __half* bufB2   = bufB + (size_t)N * 64;

    int gG = (N + 63) / 64;
    int gA = (N + 31) / 32;

    hipMemsetAsync(d_ws, 0, zbytes, stream);

    // graph build (+ fused prescale y -> bufA)
    k_rhist   <<<NC, 1024, 0, stream>>>(dstI, H, E, NC, NB);
    k_scanA   <<<GS, 256, 0, stream>>>(H, O, bsum, NBNC);
    k_scanB   <<<1, 512, 0, stream>>>(bsum, GS);
    k_rscatter<<<NC, 1024, 0, stream>>>(srcI, dstI, O, bsum, packed, E, NC, NB);
    k_wincsr  <<<NB, 512, 0, stream>>>(packed, O, bsum, row_start, csr, dinv, x, bufA,
                                       N, NC, NB, E);

    k_w2h3<<<128, 256, 0, stream>>>(W1, W1t, W2, W2t, W3, W3t);

    // conv1: aggregate-first (64ch), then GEMM 64->128 with bias+relu
    k_agg_h<64, 0, 0><<<dim3(gA, 1), 256, 0, stream>>>(bufA, bufA, csr, row_start, dinv,
                                                       dinv, dinv, bufB, N, 8,
                                                       batch, gsum, gcnt);            // s1
    k_gemm_mfma<64, 128, 1, false><<<gG, 256, 0, stream>>>(bufB, W1t, dinv, b1,
                                                           bufA, nullptr, N);         // h1
    // conv2: GEMM 128->128 (dinv epilogue, split halves), dual 64ch agg
    k_gemm_mfma<128, 128, 0, true><<<gG, 256, 0, stream>>>(bufA, W2t, dinv, b2,
                                                           bufB, bufB2, N);           // hn2a/b
    k_agg_h<64, 1, 0><<<dim3(gA, 2), 256, 0, stream>>>(bufB, bufB2, csr, row_start, dinv,
                                                       b2, b2 + 64, bufA, N, 16,
                                                       batch, gsum, gcnt);            // h2
    // conv3: GEMM 128->64 (dinv epilogue), agg with bias+relu + fused mean-pool
    k_gemm_mfma<128, 64, 0, false><<<gG, 256, 0, stream>>>(bufA, W3t, dinv, b3,
                                                           bufB, nullptr, N);         // hn3
    k_agg_h<64, 1, 1><<<dim3(gA, 1), 256, 0, stream>>>(bufB, bufB, csr, row_start, dinv,
                                                       b3, b3, nullptr, N, 0,
                                                       batch, gsum, gcnt);            // pool(h3)

    k_poolhead<<<(B + 3) / 4, 256, 0, stream>>>(gsum, gcnt, Wl1, bl1, Wl2, bl2,
                                                (float*)d_out, B);
}

// Round 10
// 198.508 us; speedup vs baseline: 1.6226x; 1.6226x over previous
//
#include <hip/hip_runtime.h>
#include <hip/hip_bf16.h>
#include <hip/hip_fp16.h>

#define CHUNK 8192          // edges per radix chunk
#define WN    128           // nodes per window/bucket
#define NBMAX 512           // max buckets (N <= 65536)

typedef _Float16 f16x8 __attribute__((ext_vector_type(8)));
typedef float    f32x4 __attribute__((ext_vector_type(4)));

// ============ radix partition by dst window (2-pass, LDS-local) ============

__global__ __launch_bounds__(1024) void k_rhist(const int* __restrict__ dst, int* __restrict__ H,
                                                int E, int NC, int NB) {
    __shared__ int h[NBMAX];
    int c = blockIdx.x, t = threadIdx.x;
    for (int i = t; i < NB; i += 1024) h[i] = 0;
    __syncthreads();
    int base = c * CHUNK;
    int lim = min(CHUNK, E - base);
    for (int k = t; k < lim; k += 1024) atomicAdd(&h[dst[base + k] >> 7], 1);
    __syncthreads();
    for (int i = t; i < NB; i += 1024) H[i * NC + c] = h[i];   // bucket-major
}

__global__ __launch_bounds__(256) void k_scanA(const int* __restrict__ in, int* __restrict__ out,
                                               int* __restrict__ bsum, int n) {
    __shared__ int s[256];
    int i = blockIdx.x * 256 + threadIdx.x;
    int v = (i < n) ? in[i] : 0;
    s[threadIdx.x] = v;
    __syncthreads();
    for (int off = 1; off < 256; off <<= 1) {
        int x = (threadIdx.x >= off) ? s[threadIdx.x - off] : 0;
        __syncthreads();
        s[threadIdx.x] += x;
        __syncthreads();
    }
    if (i < n) out[i] = s[threadIdx.x] - v;
    if (threadIdx.x == 255) bsum[blockIdx.x] = s[255];
}

__global__ __launch_bounds__(512) void k_scanB(int* __restrict__ bsum, int nb) {
    __shared__ int s[512];
    int t = threadIdx.x;
    int v = (t < nb) ? bsum[t] : 0;
    s[t] = v;
    __syncthreads();
    for (int off = 1; off < 512; off <<= 1) {
        int x = (t >= off) ? s[t - off] : 0;
        __syncthreads();
        s[t] += x;
        __syncthreads();
    }
    if (t < nb) bsum[t] = s[t] - v;
}

// scanC folded into consumers: global offset = O[idx] + bsum[idx >> 8]

__global__ __launch_bounds__(1024) void k_rscatter(const int* __restrict__ src, const int* __restrict__ dst,
                                                   const int* __restrict__ O, const int* __restrict__ bsum,
                                                   int* __restrict__ packed, int E, int NC, int NB) {
    __shared__ int cur[NBMAX];
    int c = blockIdx.x, t = threadIdx.x;
    for (int i = t; i < NB; i += 1024) {
        int idx = i * NC + c;
        cur[i] = O[idx] + bsum[idx >> 8];
    }
    __syncthreads();
    int base = c * CHUNK;
    int lim = min(CHUNK, E - base);
    for (int k = t; k < lim; k += 1024) {
        int d = dst[base + k];
        int p = atomicAdd(&cur[d >> 7], 1);
        packed[p] = (src[base + k] << 7) | (d & (WN - 1));
    }
}

// per-window: packed -> per-node CSR + row_start + dinv, plus fused
// prescale epilogue: y = fp16(dinv * x) for the window's nodes.
__global__ __launch_bounds__(512) void k_wincsr(const int* __restrict__ packed,
                                                const int* __restrict__ O,
                                                const int* __restrict__ bsum,
                                                int* __restrict__ row_start,
                                                int* __restrict__ csr,
                                                float* __restrict__ dinv,
                                                const float* __restrict__ x,
                                                __half* __restrict__ y,
                                                int n, int NC, int NB, int E) {
    __shared__ int cnt[WN];
    __shared__ int ss[WN];
    __shared__ int cur[WN];
    __shared__ float sdv[WN];
    int b = blockIdx.x, t = threadIdx.x;
    int i0 = b * NC;
    int s = O[i0] + bsum[i0 >> 8];
    int e;
    if (b + 1 < NB) {
        int i1 = (b + 1) * NC;
        e = O[i1] + bsum[i1 >> 8];
    } else {
        e = E;
    }
    if (t < WN) cnt[t] = 0;
    __syncthreads();
    for (int k = s + t; k < e; k += 512) atomicAdd(&cnt[packed[k] & (WN - 1)], 1);
    __syncthreads();
    int v = (t < WN) ? cnt[t] : 0;
    if (t < WN) ss[t] = v;
    __syncthreads();
    for (int off = 1; off < WN; off <<= 1) {
        int x2 = (t >= off && t < WN) ? ss[t - off] : 0;
        __syncthreads();
        if (t < WN) ss[t] += x2;
        __syncthreads();
    }
    int node = b * WN + t;
    if (t < WN) {
        int start = s + ss[t] - v;
        cur[t] = start;
        float dv = rsqrtf((float)(cnt[t] + 1));   // +1 self-loop
        sdv[t] = dv;
        if (node < n) {
            row_start[node] = start;
            dinv[node] = dv;
        }
    }
    if (b == NB - 1 && t == 0) row_start[n] = E;
    __syncthreads();
    for (int k = s + t; k < e; k += 512) {
        int r = packed[k];
        int p = atomicAdd(&cur[r & (WN - 1)], 1);
        csr[p] = r >> 7;
    }
    // fused prescale: y[node] = fp16(dinv * x[node,:])  (64 ch = 16 float4)
    int node0 = b * WN;
    for (int i = t; i < WN * 16; i += 512) {
        int nd = i >> 4, c4 = i & 15;
        int g = node0 + nd;
        if (g < n) {
            float dv = sdv[nd];
            float4 vv = ((const float4*)x)[(size_t)g * 16 + c4];
            __half2 h0 = __floats2half2_rn(vv.x * dv, vv.y * dv);
            __half2 h1 = __floats2half2_rn(vv.z * dv, vv.w * dv);
            uint2 u;
            u.x = *(unsigned int*)&h0;
            u.y = *(unsigned int*)&h1;
            ((uint2*)y)[(size_t)g * 16 + c4] = u;
        }
    }
}

// ============ all 3 weights fp32 -> fp16 transposed in one kernel ============

__global__ __launch_bounds__(256) void k_w2h3(const float* __restrict__ W1, _Float16* __restrict__ W1t,
                                              const float* __restrict__ W2, _Float16* __restrict__ W2t,
                                              const float* __restrict__ W3, _Float16* __restrict__ W3t) {
    int idx = blockIdx.x * 256 + threadIdx.x;
    if (idx < 8192) {                       // W1: 64 x 128
        int k = idx >> 7, f = idx & 127;
        W1t[f * 64 + k] = (_Float16)W1[idx];
    } else if (idx < 24576) {               // W2: 128 x 128
        int i = idx - 8192;
        int k = i >> 7, f = i & 127;
        W2t[f * 128 + k] = (_Float16)W2[i];
    } else if (idx < 32768) {               // W3: 128 x 64
        int i = idx - 24576;
        int k = i >> 6, f = i & 63;
        W3t[f * 128 + k] = (_Float16)W3[i];
    }
}

// ============ MFMA f16 GEMM: 64 rows/block, 4 waves x 16 rows ============
// EPI 0: out = fp16(acc * dinv[row]);  EPI 1: out = fp16(relu(acc + bias[col]))
// SP: split output columns into two compact F/2-wide buffers Hl / Hh.

template <int K, int F, int EPI, bool SP>
__global__ __launch_bounds__(256) void k_gemm_mfma(const __half* __restrict__ X,
                                                   const _Float16* __restrict__ Wt,
                                                   const float* __restrict__ dinv,
                                                   const float* __restrict__ bias,
                                                   __half* __restrict__ Hl,
                                                   __half* __restrict__ Hh, int n) {
    constexpr int ROWS = 64;
    constexpr int XS   = K + 8;
    __shared__ _Float16 sX[ROWS * XS];
    __shared__ _Float16 sW[F * XS];
    int row0 = blockIdx.x * ROWS;
    int t = threadIdx.x;

    const uint4* Xg = (const uint4*)X;
    for (int i = t; i < ROWS * (K / 8); i += 256) {
        int r = i / (K / 8), k8 = i % (K / 8);
        int gr = row0 + r;
        uint4 v = (gr < n) ? Xg[(size_t)gr * (K / 8) + k8] : make_uint4(0, 0, 0, 0);
        *(uint4*)&sX[r * XS + k8 * 8] = v;
    }
    const uint4* Wg = (const uint4*)Wt;
    for (int i = t; i < F * (K / 8); i += 256) {
        int f = i / (K / 8), k8 = i % (K / 8);
        *(uint4*)&sW[f * XS + k8 * 8] = Wg[i];
    }
    __syncthreads();

    int w = t >> 6, l = t & 63;
    int wrow = w * 16;
    int lr = l & 15;
    int lk = (l >> 4) * 8;
    f32x4 acc[F / 16];
#pragma unroll
    for (int c = 0; c < F / 16; ++c) acc[c] = (f32x4){0.f, 0.f, 0.f, 0.f};

#pragma unroll
    for (int kb = 0; kb < K / 32; ++kb) {
        f16x8 a = *(const f16x8*)&sX[(wrow + lr) * XS + kb * 32 + lk];
#pragma unroll
        for (int c = 0; c < F / 16; ++c) {
            f16x8 b = *(const f16x8*)&sW[(c * 16 + lr) * XS + kb * 32 + lk];
            acc[c] = __builtin_amdgcn_mfma_f32_16x16x32_f16(a, b, acc[c], 0, 0, 0);
        }
    }

    int rbase = row0 + wrow + (l >> 4) * 4;
    if (EPI == 0) {
        float dv[4];
#pragma unroll
        for (int r = 0; r < 4; ++r) dv[r] = (rbase + r < n) ? dinv[rbase + r] : 0.f;
#pragma unroll
        for (int c = 0; c < F / 16; ++c) {
            int col = c * 16 + lr;
#pragma unroll
            for (int r = 0; r < 4; ++r) {
                int gr = rbase + r;
                if (gr < n) {
                    __half hv = __float2half(acc[c][r] * dv[r]);
                    if (SP) {
                        if (c < F / 32) Hl[(size_t)gr * (F / 2) + col] = hv;
                        else            Hh[(size_t)gr * (F / 2) + col - F / 2] = hv;
                    } else {
                        Hl[(size_t)gr * F + col] = hv;
                    }
                }
            }
        }
    } else {
#pragma unroll
        for (int c = 0; c < F / 16; ++c) {
            int col = c * 16 + lr;
            float bc = bias[col];
#pragma unroll
            for (int r = 0; r < 4; ++r) {
                int gr = rbase + r;
                if (gr < n) {
                    __half hv = __float2half(fmaxf(acc[c][r] + bc, 0.f));
                    if (SP) {
                        if (c < F / 32) Hl[(size_t)gr * (F / 2) + col] = hv;
                        else            Hh[(size_t)gr * (F / 2) + col - F / 2] = hv;
                    } else {
                        Hl[(size_t)gr * F + col] = hv;
                    }
                }
            }
        }
    }
}

// ============ CSR aggregate (fp16 gather), 64-ch compact input ============
// blockIdx.y selects {HN0,bias0,col 0} vs {HN1,bias1,col F/2} (merged halves).
// EPI 0: out = fp16(dinv*acc);  EPI 1: out = fp16(relu(dinv*acc + bias))

__device__ __forceinline__ void acc8(float* a, uint4 v) {
    const __half2* h = (const __half2*)&v;
#pragma unroll
    for (int i = 0; i < 4; ++i) {
        float2 f = __half22float2(h[i]);
        a[2 * i]     += f.x;
        a[2 * i + 1] += f.y;
    }
}

template <int F, int EPI>
__global__ void k_agg_h(const __half* __restrict__ HN0, const __half* __restrict__ HN1,
                        const int* __restrict__ csr, const int* __restrict__ rs,
                        const float* __restrict__ dinv,
                        const float* __restrict__ bias0, const float* __restrict__ bias1,
                        __half* __restrict__ OUT, int n, int ostride4) {
    constexpr int LPN = F / 8;             // lanes per node (8 for F=64)
    constexpr int NPB = 256 / LPN;
    int half = blockIdx.y;
    const __half* HN = half ? HN1 : HN0;
    const float* bias = half ? bias1 : bias0;
    int ooff4 = half ? LPN : 0;
    int node = blockIdx.x * NPB + threadIdx.x / LPN;
    int l    = threadIdx.x % LPN;
    if (node >= n) return;
    const uint4* hn = (const uint4*)HN;
    size_t base = (size_t)node * LPN + l;
    float a[8];
    {
        uint4 v = hn[base];                // self (pre-scaled by dinv[self])
        const __half2* h = (const __half2*)&v;
#pragma unroll
        for (int i = 0; i < 4; ++i) {
            float2 f = __half22float2(h[i]);
            a[2 * i] = f.x; a[2 * i + 1] = f.y;
        }
    }
    int s = rs[node], e = rs[node + 1];
    int k = s;
    for (; k + 8 <= e; k += 8) {           // 8 gathers in flight
        int si[8];
#pragma unroll
        for (int u = 0; u < 8; ++u) si[u] = csr[k + u];
        uint4 v[8];
#pragma unroll
        for (int u = 0; u < 8; ++u) v[u] = hn[(size_t)si[u] * LPN + l];
#pragma unroll
        for (int u = 0; u < 8; ++u) acc8(a, v[u]);
    }
    for (; k + 4 <= e; k += 4) {
        int s0 = csr[k], s1 = csr[k + 1], s2 = csr[k + 2], s3 = csr[k + 3];
        uint4 v0 = hn[(size_t)s0 * LPN + l];
        uint4 v1 = hn[(size_t)s1 * LPN + l];
        uint4 v2 = hn[(size_t)s2 * LPN + l];
        uint4 v3 = hn[(size_t)s3 * LPN + l];
        acc8(a, v0); acc8(a, v1); acc8(a, v2); acc8(a, v3);
    }
    for (; k < e; ++k) acc8(a, hn[(size_t)csr[k] * LPN + l]);

    float dv = dinv[node];
    float o[8];
    if (EPI == 0) {
#pragma unroll
        for (int j = 0; j < 8; ++j) o[j] = a[j] * dv;
    } else {
        const float4* b4 = (const float4*)bias;
        float4 bb0 = b4[l * 2], bb1 = b4[l * 2 + 1];
        o[0] = fmaxf(fmaf(a[0], dv, bb0.x), 0.f);
        o[1] = fmaxf(fmaf(a[1], dv, bb0.y), 0.f);
        o[2] = fmaxf(fmaf(a[2], dv, bb0.z), 0.f);
        o[3] = fmaxf(fmaf(a[3], dv, bb0.w), 0.f);
        o[4] = fmaxf(fmaf(a[4], dv, bb1.x), 0.f);
        o[5] = fmaxf(fmaf(a[5], dv, bb1.y), 0.f);
        o[6] = fmaxf(fmaf(a[6], dv, bb1.z), 0.f);
        o[7] = fmaxf(fmaf(a[7], dv, bb1.w), 0.f);
    }
    uint4 u;
    __half2 p0 = __floats2half2_rn(o[0], o[1]);
    __half2 p1 = __floats2half2_rn(o[2], o[3]);
    __half2 p2 = __floats2half2_rn(o[4], o[5]);
    __half2 p3 = __floats2half2_rn(o[6], o[7]);
    u.x = *(unsigned int*)&p0; u.y = *(unsigned int*)&p1;
    u.z = *(unsigned int*)&p2; u.w = *(unsigned int*)&p3;
    ((uint4*)OUT)[(size_t)node * ostride4 + ooff4 + l] = u;
}

// ============ pooling (batch sorted -> segmented) + MLP head ============

__global__ void k_gstart(const int* __restrict__ batch, int* __restrict__ gstart,
                         int n, int B) {
    int i = blockIdx.x * 256 + threadIdx.x;
    if (i >= n) return;
    int b = batch[i];
    if (i == 0) {
        for (int g = 0; g <= b; ++g) gstart[g] = 0;
    } else {
        int prev = batch[i - 1];
        if (prev != b)
            for (int g = prev + 1; g <= b; ++g) gstart[g] = i;
    }
    if (i == n - 1)
        for (int g = b + 1; g <= B; ++g) gstart[g] = n;
}

__global__ void k_poolhead(const __half* __restrict__ H3, const int* __restrict__ gstart,
                           const float* __restrict__ Wl1, const float* __restrict__ bl1,
                           const float* __restrict__ Wl2, const float* __restrict__ bl2,
                           float* __restrict__ out, int B) {
    __shared__ float sh[4][64];
    __shared__ float shid[4][32];
    int w = threadIdx.x >> 6;
    int lane = threadIdx.x & 63;
    int g = blockIdx.x * 4 + w;
    if (g < B) {
        int s = gstart[g], e = gstart[g + 1];
        float acc = 0.f;
        for (int i = s; i < e; ++i) acc += __half2float(H3[(size_t)i * 64 + lane]);
        float cnt = fmaxf((float)(e - s), 1.f);
        sh[w][lane] = acc / cnt;
    }
    __syncthreads();
    if (g < B && lane < 32) {
        float a = bl1[lane];
        for (int k = 0; k < 64; ++k) a = fmaf(sh[w][k], Wl1[k * 32 + lane], a);
        shid[w][lane] = fmaxf(a, 0.f);
    }
    __syncthreads();
    if (g < B && lane < 10) {
        float a = bl2[lane];
        for (int k = 0; k < 32; ++k) a = fmaf(shid[w][k], Wl2[k * 10 + lane], a);
        out[g * 10 + lane] = a;
    }
}

// ============ launch ============

extern "C" void kernel_launch(void* const* d_in, const int* in_sizes, int n_in,
                              void* d_out, int out_size, void* d_ws, size_t ws_size,
                              hipStream_t stream) {
    const float* x    = (const float*)d_in[0];
    const int*   ei   = (const int*)d_in[1];
    const int*   batch= (const int*)d_in[2];
    const float* W1   = (const float*)d_in[3];
    const float* b1   = (const float*)d_in[4];
    const float* W2   = (const float*)d_in[5];
    const float* b2   = (const float*)d_in[6];
    const float* W3   = (const float*)d_in[7];
    const float* b3   = (const float*)d_in[8];
    const float* Wl1  = (const float*)d_in[9];
    const float* bl1  = (const float*)d_in[10];
    const float* Wl2  = (const float*)d_in[11];
    const float* bl2  = (const float*)d_in[12];

    const int N  = in_sizes[0] / 64;
    const int E  = in_sizes[1] / 2;
    const int B  = out_size / 10;
    const int NB = (N + WN - 1) / WN;
    const int NC = (E + CHUNK - 1) / CHUNK;
    const int NBNC = NB * NC;
    const int GS = (NBNC + 255) / 256;
    const int* srcI = ei;
    const int* dstI = ei + E;

    char* p = (char*)d_ws;
    auto alloc = [&](size_t bytes) {
        char* r = p;
        p += (bytes + 255) & ~(size_t)255;
        return r;
    };
    int*   H        = (int*)alloc((size_t)NBNC * 4);
    int*   O        = (int*)alloc((size_t)NBNC * 4);
    int*   bsum     = (int*)alloc(2048 * 4);
    int*   packed   = (int*)alloc((size_t)E * 4);
    int*   csr      = (int*)alloc((size_t)E * 4);
    int*   row_start= (int*)alloc((size_t)(N + 1) * 4);
    float* dinv     = (float*)alloc((size_t)N * 4);
    int*   gstart   = (int*)alloc((size_t)(B + 1) * 4);
    _Float16* W1t   = (_Float16*)alloc((size_t)64 * 128 * 2);
    _Float16* W2t   = (_Float16*)alloc((size_t)128 * 128 * 2);
    _Float16* W3t   = (_Float16*)alloc((size_t)128 * 64 * 2);
    __half* bufA    = (__half*)alloc((size_t)N * 128 * 2);
    __half* bufB    = (__half*)alloc((size_t)N * 128 * 2);
    __half* bufB2   = bufB + (size_t)N * 64;

    int gN = (N + 255) / 256;
    int gG = (N + 63) / 64;
    int gA = (N + 31) / 32;

    // graph build (+ fused prescale y -> bufA)
    k_rhist   <<<NC, 1024, 0, stream>>>(dstI, H, E, NC, NB);
    k_scanA   <<<GS, 256, 0, stream>>>(H, O, bsum, NBNC);
    k_scanB   <<<1, 512, 0, stream>>>(bsum, GS);
    k_rscatter<<<NC, 1024, 0, stream>>>(srcI, dstI, O, bsum, packed, E, NC, NB);
    k_wincsr  <<<NB, 512, 0, stream>>>(packed, O, bsum, row_start, csr, dinv, x, bufA,
                                       N, NC, NB, E);

    k_w2h3<<<128, 256, 0, stream>>>(W1, W1t, W2, W2t, W3, W3t);

    // conv1: aggregate-first (64ch), then GEMM 64->128 with bias+relu
    k_agg_h<64, 0><<<dim3(gA, 1), 256, 0, stream>>>(bufA, bufA, csr, row_start, dinv,
                                                    dinv, dinv, bufB, N, 8);          // s1
    k_gemm_mfma<64, 128, 1, false><<<gG, 256, 0, stream>>>(bufB, W1t, dinv, b1,
                                                           bufA, nullptr, N);         // h1
    // conv2: GEMM 128->128 (dinv epilogue, split halves), dual 64ch agg
    k_gemm_mfma<128, 128, 0, true><<<gG, 256, 0, stream>>>(bufA, W2t, dinv, b2,
                                                           bufB, bufB2, N);           // hn2a/b
    k_agg_h<64, 1><<<dim3(gA, 2), 256, 0, stream>>>(bufB, bufB2, csr, row_start, dinv,
                                                    b2, b2 + 64, bufA, N, 16);        // h2
    // conv3: GEMM 128->64 (dinv epilogue), agg with bias+relu
    k_gemm_mfma<128, 64, 0, false><<<gG, 256, 0, stream>>>(bufA, W3t, dinv, b3,
                                                           bufB, nullptr, N);         // hn3
    k_agg_h<64, 1><<<dim3(gA, 1), 256, 0, stream>>>(bufB, bufB, csr, row_start, dinv,
                                                    b3, b3, bufB2, N, 8);             // h3

    k_gstart  <<<gN, 256, 0, stream>>>(batch, gstart, N, B);
    k_poolhead<<<(B + 3) / 4, 256, 0, stream>>>(bufB2, gstart, Wl1, bl1, Wl2, bl2,
                                                (float*)d_out, B);
}